// Round 3
// baseline (482.701 us; speedup 1.0000x reference)
//
#include <hip/hip_runtime.h>

// Round 6: occupancy pass — 2 blocks/CU (8 waves, 2/SIMD).
//   LDS 146KB -> 81920 B exactly: W2 frags read from global (L1/L2-resident),
//   H buffers overlay the wave-private feats region (B-frags preloaded to regs),
//   b1 folded into MFMA K=48 column, b2/b3 hoisted from global to VGPRs.
//   featsL: 128 B/px, XOR chunk swizzle (conflict-free quarter-wave phases).

#define NPX (1u << 20)

using bf16x8 = __attribute__((ext_vector_type(8))) __bf16;
using f32x4  = __attribute__((ext_vector_type(4))) float;

__device__ __forceinline__ unsigned f2bf(float f) {
    unsigned u = __float_as_uint(f);
    u += 0x7fffu + ((u >> 16) & 1u);   // RNE; inputs finite
    return u >> 16;
}

// ---- ws layout (ushort offsets): weight frags only ----
#define WS1_OFF 0        // [mt=8][kb=2][lane=64][8]  A-frags of W1^T (K-pad 48->64; k=48 = b1)
#define WS2_OFF 8192     // [mt=8][kb=4][lane=64][8]  A-frags of W2^T
#define WS3_OFF 24576    // [kb=4][lane=64][8]        A-frags of W3^T

__global__ __launch_bounds__(256)
void prep_weights(const float* __restrict__ w1, const float* __restrict__ b1,
                  const float* __restrict__ w2, const float* __restrict__ w3,
                  unsigned short* __restrict__ ws) {
    const int gid = blockIdx.x * 256 + threadIdx.x;   // 13 blocks x 256 = 3328 slots
    if (gid < 1024) {   // ws1 (feature order k = 3*c + t; w1 row = t*16 + c; k=48 -> b1)
        const int s = gid;
        const int mt = s >> 7, kb = (s >> 6) & 1, lane = s & 63;
        const int q = lane >> 4, ln = lane & 15;
#pragma unroll
        for (int j = 0; j < 8; ++j) {
            const int k = kb * 32 + q * 8 + j;
            float val = 0.f;
            if (k < 48) { const int c = k / 3, t = k - 3 * c; val = w1[(t * 16 + c) * 128 + mt * 16 + ln]; }
            else if (k == 48) val = b1[mt * 16 + ln];   // bias column (B side supplies 1.0)
            ws[WS1_OFF + s * 8 + j] = (unsigned short)f2bf(val);
        }
    } else if (gid < 3072) {   // ws2
        const int s2 = gid - 1024;
        const int mt = s2 >> 8, kb = (s2 >> 6) & 3, lane = s2 & 63;
        const int q = lane >> 4, ln = lane & 15;
#pragma unroll
        for (int j = 0; j < 8; ++j) {
            const int k = kb * 32 + q * 8 + j;
            ws[WS2_OFF + s2 * 8 + j] = (unsigned short)f2bf(w2[k * 128 + mt * 16 + ln]);
        }
    } else if (gid < 3328) {   // ws3
        const int s3 = gid - 3072;
        const int kb = s3 >> 6, lane = s3 & 63;
        const int q = lane >> 4, ln = lane & 15;
#pragma unroll
        for (int j = 0; j < 8; ++j) {
            const int k = kb * 32 + q * 8 + j;
            ws[WS3_OFF + s3 * 8 + j] = (unsigned short)f2bf(w3[k * 16 + ln]);
        }
    }
}

// ===================== fused kernel =====================
// 512 blocks = 16 batches x 32 strips of 8 rows; 256 threads = 4 waves.
// Thread t = column t for Sobel; wave w produces feats/sel for exactly the
// 64-px tile wave w consumes (wave-private region; H overlays it during MLP).
#define XS_W 256

// LDS layout (bytes), total 81920 -> 2 blocks/CU (2 x 81920 = 163840 = full pool):
#define SM_XS    0       // float xs[3][16][256]                  = 49152
#define SM_WR    49152   // 4 wave regions x 8192                 = 32768
//   region (per wave): feats phase: px[64] x 128B (chunks 0..5 data, 6 sel, XOR swz)
//                      MLP phase:   Ha[4096] + Hb[4096] (feats already in regs)
#define SM_TOTAL 81920

#define H_SWZ(j, ln) ((((j) ^ ((ln) & 7)) << 4))

extern "C" __global__ __launch_bounds__(256, 2)
void fused_kernel(const float* __restrict__ x, const float* __restrict__ fmask,
                  const unsigned short* __restrict__ wf,
                  const float* __restrict__ b2, const float* __restrict__ b3,
                  float* __restrict__ out) {
    extern __shared__ char smem[];
    float (*xs)[16][XS_W] = (float (*)[16][XS_W])(smem + SM_XS);
    char* fL = smem + SM_WR;               // feats base, indexed by t*128 directly

    const int t = threadIdx.x;
    const int wv = t >> 6, lane = t & 63;
    const int q = lane >> 4, ln = lane & 15;
    char* region = smem + SM_WR + wv * 8192;   // this wave's feats / H region
    char* Ha = region;
    char* Hb = region + 4096;

    const int bb = blockIdx.x >> 5;
    const int h0 = (blockIdx.x & 31) << 3;
    const float* xb = x + ((size_t)bb << 20);

    // ---- W1/W3 frags -> VGPRs ----
    bf16x8 W1f[8][2], W3f[4];
#pragma unroll
    for (int mt = 0; mt < 8; ++mt) {
        W1f[mt][0] = *(const bf16x8*)(wf + WS1_OFF + ((mt * 2 + 0) * 64 + lane) * 8);
        W1f[mt][1] = *(const bf16x8*)(wf + WS1_OFF + ((mt * 2 + 1) * 64 + lane) * 8);
    }
#pragma unroll
    for (int kb = 0; kb < 4; ++kb)
        W3f[kb] = *(const bf16x8*)(wf + WS3_OFF + (kb * 64 + lane) * 8);

    // ---- Sobel column constants ----
    const int col = t;
    const int cL = (col > 0)   ? col - 1 : 0;
    const int cR = (col < 255) ? col + 1 : 255;
    const float mL = (col > 0)   ? 1.f : 0.f;
    const float mR = (col < 255) ? 1.f : 0.f;

    float4 stg[4];
#define STAGE_ISSUE(r2) do { _Pragma("unroll")                                   \
    for (int i = 0; i < 4; ++i) {                                                \
        const int idx = t + i * 256;                                             \
        const int ch = idx >> 6; const int c4 = (idx & 63) << 2;                 \
        float4 v = make_float4(0.f, 0.f, 0.f, 0.f);                              \
        if ((unsigned)(r2) < 256u)                                               \
            v = *(const float4*)(xb + ((size_t)ch << 16) + (r2) * 256 + c4);     \
        stg[i] = v; } } while (0)
#define STAGE_STORE(slot) do { _Pragma("unroll")                                 \
    for (int i = 0; i < 4; ++i) {                                                \
        const int idx = t + i * 256;                                             \
        const int ch = idx >> 6; const int c4 = (idx & 63) << 2;                 \
        *(float4*)&xs[slot][ch][c4] = stg[i]; } } while (0)

    STAGE_ISSUE(h0 - 1); STAGE_STORE((h0 + 2) % 3);
    STAGE_ISSUE(h0);     STAGE_STORE(h0 % 3);
    STAGE_ISSUE(h0 + 1);

    for (int rr = 0; rr < 8; ++rr) {
        const int r = h0 + rr;
        STAGE_STORE((r + 1) % 3);        // waits on in-flight row r+1
        __syncthreads();                 // xs slots r-1, r, r+1 valid
        if (rr < 7) STAGE_ISSUE(r + 2);  // next row's loads fly under Sobel+MFMA
        const float fv = fmask[((size_t)bb << 16) + r * 256 + col];

        // ---- Sobel + pack (thread = column) ----
        const int sT = (r + 2) % 3, sC = r % 3, sB = (r + 1) % 3;
        unsigned pk[24];
        unsigned carry = 0;
        float selv = 0.f;
#pragma unroll
        for (int c = 0; c < 16; ++c) {
            const float* rT = xs[sT][c];
            const float* rC = xs[sC][c];
            const float* rB = xs[sB][c];
            const float v00 = rT[cL] * mL, v01 = rT[col], v02 = rT[cR] * mR;
            const float v10 = rC[cL] * mL, v11 = rC[col], v12 = rC[cR] * mR;
            const float v20 = rB[cL] * mL, v21 = rB[col], v22 = rB[cR] * mR;
            const float sx = (v02 + 2.f * v12 + v22) - (v00 + 2.f * v10 + v20);
            const float sy = (v20 + 2.f * v21 + v22) - (v00 + 2.f * v01 + v02);
            if (c == 3) {   // exact fp32 3x3 maxpool of alpha (x >= 0 -> zero-pad safe)
                float mx = fmaxf(fmaxf(fmaxf(v00, v01), fmaxf(v02, v10)),
                                 fmaxf(fmaxf(v11, v12), fmaxf(fmaxf(v20, v21), v22)));
                selv = (mx > 0.1f) ? 1.f : 0.f;
            }
            const unsigned ux = f2bf(v11), usx = f2bf(sx), usy = f2bf(sy);
            if ((c & 1) == 0) { pk[(c >> 1) * 3] = ux | (usx << 16); carry = usy; }
            else { pk[(c >> 1) * 3 + 1] = carry | (ux << 16);
                   pk[(c >> 1) * 3 + 2] = usx | (usy << 16); }
        }
        // ---- feats -> wave region, XOR chunk swizzle; sel in chunk 6 ----
        {
            uint4* fb = (uint4*)(fL + t * 128);
            const int sw = t & 7;
#pragma unroll
            for (int c = 0; c < 6; ++c)
                fb[c ^ sw] = make_uint4(pk[c * 4 + 0], pk[c * 4 + 1], pk[c * 4 + 2], pk[c * 4 + 3]);
            *(float*)(fb + (6 ^ sw)) = (fv != 0.f) ? selv : 0.f;
        }
        __syncthreads();   // guards xs slot reuse next iter

        // ---- preload all 4 subs' B-frags + sel to regs (region becomes H) ----
        bf16x8 Bk0[4], Bk1[4];
        float sv[4];
        const int rsw = ln & 7;
#pragma unroll
        for (int s = 0; s < 4; ++s) {
            const char* fp = region + (s * 16 + ln) * 128;
            Bk0[s] = *(const bf16x8*)(fp + ((q ^ rsw) << 4));
            bf16x8 t1 = {};
            if (q < 2)       t1 = *(const bf16x8*)(fp + (((4 + q) ^ rsw) << 4));
            else if (q == 2) t1[0] = (__bf16)1.0f;   // ones column k=48 (bias)
            Bk1[s] = t1;
            sv[s] = *(const float*)(fp + ((6 ^ rsw) << 4));
        }

        // ---- MLP: 2 pairs of subs (Ha/Hb), W2 A-frags from global (L1/L2) ----
#pragma unroll
        for (int p = 0; p < 2; ++p) {
            const int sA = 2 * p, sB2 = 2 * p + 1;
            // ---- layer 1 (bias via k=48 column) ----
#pragma unroll
            for (int mt = 0; mt < 8; ++mt) {
                f32x4 aA = {}, aB = {};
                aA = __builtin_amdgcn_mfma_f32_16x16x32_bf16(W1f[mt][0], Bk0[sA], aA, 0, 0, 0);
                aB = __builtin_amdgcn_mfma_f32_16x16x32_bf16(W1f[mt][0], Bk0[sB2], aB, 0, 0, 0);
                aA = __builtin_amdgcn_mfma_f32_16x16x32_bf16(W1f[mt][1], Bk1[sA], aA, 0, 0, 0);
                aB = __builtin_amdgcn_mfma_f32_16x16x32_bf16(W1f[mt][1], Bk1[sB2], aB, 0, 0, 0);
                const unsigned a01 = f2bf(fmaxf(aA[0], 0.f)) | (f2bf(fmaxf(aA[1], 0.f)) << 16);
                const unsigned a23 = f2bf(fmaxf(aA[2], 0.f)) | (f2bf(fmaxf(aA[3], 0.f)) << 16);
                const unsigned b01 = f2bf(fmaxf(aB[0], 0.f)) | (f2bf(fmaxf(aB[1], 0.f)) << 16);
                const unsigned b23 = f2bf(fmaxf(aB[2], 0.f)) | (f2bf(fmaxf(aB[3], 0.f)) << 16);
                const int off = ln * 256 + H_SWZ(mt * 2 + (q >> 1), ln) + ((q & 1) << 3);
                *(uint2*)(Ha + off) = make_uint2(a01, a23);
                *(uint2*)(Hb + off) = make_uint2(b01, b23);
            }
            bf16x8 B2A[4], B2B[4];
#pragma unroll
            for (int kb = 0; kb < 4; ++kb) {
                const int off = ln * 256 + H_SWZ(kb * 4 + q, ln);
                B2A[kb] = *(const bf16x8*)(Ha + off);
                B2B[kb] = *(const bf16x8*)(Hb + off);
            }
            // ---- layer 2: W2 A-frags from global (L1-resident); each feeds 2 MFMAs ----
#pragma unroll
            for (int mt = 0; mt < 8; ++mt) {
                const f32x4 bz = *(const f32x4*)(b2 + mt * 16 + q * 4);
                f32x4 aA = bz, aB = bz;
#pragma unroll
                for (int kb = 0; kb < 4; ++kb) {
                    const bf16x8 Af = *(const bf16x8*)(wf + WS2_OFF + ((mt * 4 + kb) * 64 + lane) * 8);
                    aA = __builtin_amdgcn_mfma_f32_16x16x32_bf16(Af, B2A[kb], aA, 0, 0, 0);
                    aB = __builtin_amdgcn_mfma_f32_16x16x32_bf16(Af, B2B[kb], aB, 0, 0, 0);
                }
                const unsigned a01 = f2bf(fmaxf(aA[0], 0.f)) | (f2bf(fmaxf(aA[1], 0.f)) << 16);
                const unsigned a23 = f2bf(fmaxf(aA[2], 0.f)) | (f2bf(fmaxf(aA[3], 0.f)) << 16);
                const unsigned b01 = f2bf(fmaxf(aB[0], 0.f)) | (f2bf(fmaxf(aB[1], 0.f)) << 16);
                const unsigned b23 = f2bf(fmaxf(aB[2], 0.f)) | (f2bf(fmaxf(aB[3], 0.f)) << 16);
                const int off = ln * 256 + H_SWZ(mt * 2 + (q >> 1), ln) + ((q & 1) << 3);
                *(uint2*)(Ha + off) = make_uint2(a01, a23);
                *(uint2*)(Hb + off) = make_uint2(b01, b23);
            }
            // ---- layer 3 ----
            const f32x4 bz3 = *(const f32x4*)(b3 + q * 4);
            f32x4 a3A = bz3, a3B = bz3;
#pragma unroll
            for (int kb = 0; kb < 4; ++kb) {
                const int off = ln * 256 + H_SWZ(kb * 4 + q, ln);
                const bf16x8 B3A = *(const bf16x8*)(Ha + off);
                const bf16x8 B3B = *(const bf16x8*)(Hb + off);
                a3A = __builtin_amdgcn_mfma_f32_16x16x32_bf16(W3f[kb], B3A, a3A, 0, 0, 0);
                a3B = __builtin_amdgcn_mfma_f32_16x16x32_bf16(W3f[kb], B3B, a3B, 0, 0, 0);
            }
            // ---- epilogue: mask + transpose bounce via Ha (dead) + 128B stores ----
            const float svA = sv[sA];
            const float svB = sv[sB2];
            float* bounce = (float*)Ha;   // [ch][32px] stride 34 dwords
#pragma unroll
            for (int r4 = 0; r4 < 4; ++r4) {
                bounce[(q * 4 + r4) * 34 + ln]      = a3A[r4] * svA;
                bounce[(q * 4 + r4) * 34 + 16 + ln] = a3B[r4] * svB;
            }
            const int px32 = lane & 31;
            const int chb  = lane >> 5;
            float* orow = out + (((size_t)(bb * 16)) << 16) + (size_t)r * 256
                        + wv * 64 + p * 32 + px32;
#pragma unroll
            for (int i = 0; i < 8; ++i) {
                const int ch = chb + 2 * i;
                orow[(size_t)ch << 16] = bounce[ch * 34 + px32];
            }
        }
    }
#undef STAGE_ISSUE
#undef STAGE_STORE
}

extern "C" void kernel_launch(void* const* d_in, const int* in_sizes, int n_in,
                              void* d_out, int out_size, void* d_ws, size_t ws_size,
                              hipStream_t stream) {
    (void)in_sizes; (void)n_in; (void)out_size; (void)ws_size;
    const float* x  = (const float*)d_in[0];
    const float* fm = (const float*)d_in[1];
    const float* w1 = (const float*)d_in[2];
    const float* b1 = (const float*)d_in[3];
    const float* w2 = (const float*)d_in[4];
    const float* b2 = (const float*)d_in[5];
    const float* w3 = (const float*)d_in[6];
    const float* b3 = (const float*)d_in[7];
    float* o = (float*)d_out;
    unsigned short* ws = (unsigned short*)d_ws;

    prep_weights<<<dim3(13), dim3(256), 0, stream>>>(w1, b1, w2, w3, ws);

    hipFuncSetAttribute((const void*)fused_kernel,
                        hipFuncAttributeMaxDynamicSharedMemorySize, SM_TOTAL);
    fused_kernel<<<dim3(512), dim3(256), SM_TOTAL, stream>>>(x, fm, ws, b2, b3, o);
}

// Round 4
// 314.106 us; speedup vs baseline: 1.5367x; 1.5367x over previous
//
#include <hip/hip_runtime.h>

// Round 7: 512-thread block, 2 rows/iteration, 2 waves/SIMD, W2 back in LDS.
//   - LDS 163840 B exactly: xs[4][16][256] 64K + W2 frags 32K + 8 wave-regions 64K
//   - x staged via global_load_lds width16 (no staging VGPRs, async under MLP)
//   - W1/W3 frags LDS-bounced once per block (ws fetch 96->27 MB)
//   - b1 folded as k=48 MFMA column (R6-verified); b2/b3 in VGPRs
//   - MLP: feats preload->regs, H overlays wave region, bounce transpose, 256B stores

#define NPX (1u << 20)

using bf16x8 = __attribute__((ext_vector_type(8))) __bf16;
using f32x4  = __attribute__((ext_vector_type(4))) float;

__device__ __forceinline__ unsigned f2bf(float f) {
    unsigned u = __float_as_uint(f);
    u += 0x7fffu + ((u >> 16) & 1u);   // RNE; inputs finite
    return u >> 16;
}

// ---- ws layout (ushort offsets): weight frags only ----
#define WS1_OFF 0        // [mt=8][kb=2][lane=64][8]  A-frags of W1^T (K-pad 48->64; k=48 = b1)
#define WS2_OFF 8192     // [mt=8][kb=4][lane=64][8]  A-frags of W2^T
#define WS3_OFF 24576    // [kb=4][lane=64][8]        A-frags of W3^T

__global__ __launch_bounds__(256)
void prep_weights(const float* __restrict__ w1, const float* __restrict__ b1,
                  const float* __restrict__ w2, const float* __restrict__ w3,
                  unsigned short* __restrict__ ws) {
    const int gid = blockIdx.x * 256 + threadIdx.x;   // 13 blocks x 256 = 3328 slots
    if (gid < 1024) {   // ws1 (feature order k = 3*c + t; w1 row = t*16 + c; k=48 -> b1)
        const int s = gid;
        const int mt = s >> 7, kb = (s >> 6) & 1, lane = s & 63;
        const int q = lane >> 4, ln = lane & 15;
#pragma unroll
        for (int j = 0; j < 8; ++j) {
            const int k = kb * 32 + q * 8 + j;
            float val = 0.f;
            if (k < 48) { const int c = k / 3, t = k - 3 * c; val = w1[(t * 16 + c) * 128 + mt * 16 + ln]; }
            else if (k == 48) val = b1[mt * 16 + ln];   // bias column (B side supplies 1.0)
            ws[WS1_OFF + s * 8 + j] = (unsigned short)f2bf(val);
        }
    } else if (gid < 3072) {   // ws2
        const int s2 = gid - 1024;
        const int mt = s2 >> 8, kb = (s2 >> 6) & 3, lane = s2 & 63;
        const int q = lane >> 4, ln = lane & 15;
#pragma unroll
        for (int j = 0; j < 8; ++j) {
            const int k = kb * 32 + q * 8 + j;
            ws[WS2_OFF + s2 * 8 + j] = (unsigned short)f2bf(w2[k * 128 + mt * 16 + ln]);
        }
    } else if (gid < 3328) {   // ws3
        const int s3 = gid - 3072;
        const int kb = s3 >> 6, lane = s3 & 63;
        const int q = lane >> 4, ln = lane & 15;
#pragma unroll
        for (int j = 0; j < 8; ++j) {
            const int k = kb * 32 + q * 8 + j;
            ws[WS3_OFF + s3 * 8 + j] = (unsigned short)f2bf(w3[k * 16 + ln]);
        }
    }
}

// ===================== fused kernel =====================
// 512 blocks = 16 batches x 32 strips of 8 rows; 512 threads = 8 waves.
// Iteration i covers rows r0=h0+2i, r0+1: waves 0-3 -> row r0 (cols 64w..),
// waves 4-7 -> row r0+1. Wave w's region holds feats/H for its own 64-px tile.

// LDS layout (bytes), total 163840 (full pool, 1 block/CU, 8 waves = 2/SIMD):
#define SM_XS    0       // float xs[4][16][256] rolling row window   = 65536
#define SM_W2    65536   // W2 A-frags (also W1/W3 bounce at init)    = 32768
#define SM_WR    98304   // 8 wave regions x 8192                     = 65536
#define SM_TOTAL 163840

#define H_SWZ(j, ln) ((((j) ^ ((ln) & 7)) << 4))

#define GLDS16(gp, lp) __builtin_amdgcn_global_load_lds(                     \
    (const __attribute__((address_space(1))) void*)(gp),                     \
    (__attribute__((address_space(3))) void*)(lp), 16, 0, 0)

// stage one (ch,row) pair -> xs[row&3][ch][*]; row/ch wave-uniform.
// dest = wave-uniform base + lane*16 (global_load_lds semantics); OOB rows zero-fill.
#define STAGE_UNIT(chv, rowv) do {                                           \
        const int _sl = (rowv) & 3;                                          \
        char* _ld = smem + SM_XS + (size_t)(((_sl) * 16 + (chv)) * 256) * 4; \
        if ((unsigned)(rowv) < 256u) {                                       \
            const float* _gs = xb + ((size_t)(chv) << 16)                    \
                             + (size_t)(unsigned)(rowv) * 256 + lane * 4;    \
            GLDS16(_gs, _ld);                                                \
        } else {                                                             \
            *(float4*)(_ld + lane * 16) = make_float4(0.f, 0.f, 0.f, 0.f);   \
        } } while (0)

extern "C" __global__ __launch_bounds__(512, 2)
void fused_kernel(const float* __restrict__ x, const float* __restrict__ fmask,
                  const unsigned short* __restrict__ wf,
                  const float* __restrict__ b2, const float* __restrict__ b3,
                  float* __restrict__ out) {
    extern __shared__ char smem[];
    float (*xs)[16][256] = (float (*)[16][256])(smem + SM_XS);
    char* W2L = smem + SM_W2;

    const int t = threadIdx.x;
    const int wv = t >> 6, lane = t & 63;
    const int q = lane >> 4, ln = lane & 15;
    const int rhalf = t >> 8;              // 0: waves 0-3, 1: waves 4-7
    const int col = t & 255;
    char* region = smem + SM_WR + wv * 8192;   // feats phase / H + bounce in MLP phase
    char* H = region;                          // 4096 B
    float* bounce = (float*)(region + 4096);   // [16 ch][64 px] = 4096 B

    const int bb = blockIdx.x >> 5;
    const int h0 = (blockIdx.x & 31) << 3;
    const float* xb = x + ((size_t)bb << 20);

    // ---- stage W1/W3 frag tables through LDS (ws read once per block) ----
    {
        const uint4* s1 = (const uint4*)(wf + WS1_OFF);   // 1024 uint4 = 16 KB
        uint4* dW = (uint4*)W2L;
        dW[t]       = s1[t];
        dW[t + 512] = s1[t + 512];
        if (t < 256) dW[1024 + t] = ((const uint4*)(wf + WS3_OFF))[t];   // 4 KB
    }
    __syncthreads();
    bf16x8 W1f[8][2], W3f[4];
#pragma unroll
    for (int mt = 0; mt < 8; ++mt) {
        W1f[mt][0] = *(const bf16x8*)(W2L + ((mt * 2 + 0) * 64 + lane) * 16);
        W1f[mt][1] = *(const bf16x8*)(W2L + ((mt * 2 + 1) * 64 + lane) * 16);
    }
#pragma unroll
    for (int kb = 0; kb < 4; ++kb)
        W3f[kb] = *(const bf16x8*)(W2L + 16384 + (kb * 64 + lane) * 16);
    __syncthreads();
    {   // now stage W2 frags (overwrites the bounce area)
        const uint4* s2 = (const uint4*)(wf + WS2_OFF);   // 2048 uint4 = 32 KB
        uint4* dW = (uint4*)W2L;
#pragma unroll
        for (int i2 = 0; i2 < 4; ++i2) dW[t + i2 * 512] = s2[t + i2 * 512];
    }
    // ---- biases -> VGPRs (loop-invariant) ----
    f32x4 bz2[8];
#pragma unroll
    for (int mt = 0; mt < 8; ++mt) bz2[mt] = *(const f32x4*)(b2 + mt * 16 + q * 4);
    const f32x4 bz3 = *(const f32x4*)(b3 + q * 4);

    // ---- Sobel column constants ----
    const int cL = (col > 0)   ? col - 1 : 0;
    const int cR = (col < 255) ? col + 1 : 255;
    const float mL = (col > 0)   ? 1.f : 0.f;
    const float mR = (col < 255) ? 1.f : 0.f;

    // ---- prologue: stage rows h0-1..h0+2 (64 units, 8 per wave) ----
#pragma unroll
    for (int k = 0; k < 8; ++k) {
        const int u = wv + 8 * k;                  // 0..63, each once
        STAGE_UNIT(u >> 2, h0 - 1 + (u & 3));
    }

    for (int i = 0; i < 4; ++i) {
        const int r0 = h0 + 2 * i;
        const int r  = r0 + rhalf;
        __syncthreads();   // staged rows complete (barrier drains vmcnt); W2L ready
        const float fv = fmask[((size_t)bb << 16) + (size_t)r * 256 + col];

        // ---- Sobel + pack (thread = (rhalf, col)) ----
        const int sT = (r - 1) & 3, sC = r & 3, sB = (r + 1) & 3;
        unsigned pk[24];
        unsigned carry = 0;
        float selv = 0.f;
#pragma unroll
        for (int c = 0; c < 16; ++c) {
            const float* rT = xs[sT][c];
            const float* rC = xs[sC][c];
            const float* rB = xs[sB][c];
            const float v00 = rT[cL] * mL, v01 = rT[col], v02 = rT[cR] * mR;
            const float v10 = rC[cL] * mL, v11 = rC[col], v12 = rC[cR] * mR;
            const float v20 = rB[cL] * mL, v21 = rB[col], v22 = rB[cR] * mR;
            const float sx = (v02 + 2.f * v12 + v22) - (v00 + 2.f * v10 + v20);
            const float sy = (v20 + 2.f * v21 + v22) - (v00 + 2.f * v01 + v02);
            if (c == 3) {   // exact fp32 3x3 maxpool of alpha (x >= 0 -> zero-pad safe)
                float mx = fmaxf(fmaxf(fmaxf(v00, v01), fmaxf(v02, v10)),
                                 fmaxf(fmaxf(v11, v12), fmaxf(fmaxf(v20, v21), v22)));
                selv = (mx > 0.1f) ? 1.f : 0.f;
            }
            const unsigned ux = f2bf(v11), usx = f2bf(sx), usy = f2bf(sy);
            if ((c & 1) == 0) { pk[(c >> 1) * 3] = ux | (usx << 16); carry = usy; }
            else { pk[(c >> 1) * 3 + 1] = carry | (ux << 16);
                   pk[(c >> 1) * 3 + 2] = usx | (usy << 16); }
        }
        // ---- feats -> wave region (128 B/px, XOR chunk swizzle; sel in chunk 6) ----
        {
            uint4* fb = (uint4*)(region + lane * 128);
            const int sw = lane & 7;
#pragma unroll
            for (int c = 0; c < 6; ++c)
                fb[c ^ sw] = make_uint4(pk[c * 4 + 0], pk[c * 4 + 1], pk[c * 4 + 2], pk[c * 4 + 3]);
            *(float*)(fb + (6 ^ sw)) = (fv != 0.f) ? selv : 0.f;
        }
        // ---- preload all 4 subs' B-frags + sel to regs (region becomes H/bounce) ----
        bf16x8 Bk0[4], Bk1[4];
        float sv[4];
        const int rsw = ln & 7;
#pragma unroll
        for (int s = 0; s < 4; ++s) {
            const char* fp = region + (s * 16 + ln) * 128;
            Bk0[s] = *(const bf16x8*)(fp + ((q ^ rsw) << 4));
            bf16x8 t1 = {};
            if (q < 2)       t1 = *(const bf16x8*)(fp + (((4 + q) ^ rsw) << 4));
            else if (q == 2) t1[0] = (__bf16)1.0f;   // ones column k=48 (bias)
            Bk1[s] = t1;
            sv[s] = *(const float*)(fp + ((6 ^ rsw) << 4));
        }
        __syncthreads();   // all waves done reading xs -> safe to restage oldest slots
        if (i < 3) {       // rows r0+3, r0+4 fly under the MLP phase
#pragma unroll
            for (int k = 0; k < 4; ++k) {
                const int u = wv + 8 * k;          // 0..31, each once
                STAGE_UNIT(u >> 1, r0 + 3 + (u & 1));
            }
        }

        // ---- MLP: 4 subs sequential; single H; W2 A-frags from LDS ----
#pragma unroll
        for (int sub = 0; sub < 4; ++sub) {
            // layer 1 (bias via k=48 column)
#pragma unroll
            for (int mt = 0; mt < 8; ++mt) {
                f32x4 a = {};
                a = __builtin_amdgcn_mfma_f32_16x16x32_bf16(W1f[mt][0], Bk0[sub], a, 0, 0, 0);
                a = __builtin_amdgcn_mfma_f32_16x16x32_bf16(W1f[mt][1], Bk1[sub], a, 0, 0, 0);
                const unsigned r01 = f2bf(fmaxf(a[0], 0.f)) | (f2bf(fmaxf(a[1], 0.f)) << 16);
                const unsigned r23 = f2bf(fmaxf(a[2], 0.f)) | (f2bf(fmaxf(a[3], 0.f)) << 16);
                *(uint2*)(H + ln * 256 + H_SWZ(mt * 2 + (q >> 1), ln) + ((q & 1) << 3))
                    = make_uint2(r01, r23);
            }
            bf16x8 B2[4];
#pragma unroll
            for (int kb = 0; kb < 4; ++kb)
                B2[kb] = *(const bf16x8*)(H + ln * 256 + H_SWZ(kb * 4 + q, ln));
            // layer 2 (W2 A-frags from LDS)
#pragma unroll
            for (int mt = 0; mt < 8; ++mt) {
                f32x4 a = bz2[mt];
#pragma unroll
                for (int kb = 0; kb < 4; ++kb) {
                    const bf16x8 Af = *(const bf16x8*)(W2L + ((mt * 4 + kb) * 64 + lane) * 16);
                    a = __builtin_amdgcn_mfma_f32_16x16x32_bf16(Af, B2[kb], a, 0, 0, 0);
                }
                const unsigned r01 = f2bf(fmaxf(a[0], 0.f)) | (f2bf(fmaxf(a[1], 0.f)) << 16);
                const unsigned r23 = f2bf(fmaxf(a[2], 0.f)) | (f2bf(fmaxf(a[3], 0.f)) << 16);
                *(uint2*)(H + ln * 256 + H_SWZ(mt * 2 + (q >> 1), ln) + ((q & 1) << 3))
                    = make_uint2(r01, r23);
            }
            // layer 3
            f32x4 a3 = bz3;
#pragma unroll
            for (int kb = 0; kb < 4; ++kb) {
                const bf16x8 B3 = *(const bf16x8*)(H + ln * 256 + H_SWZ(kb * 4 + q, ln));
                a3 = __builtin_amdgcn_mfma_f32_16x16x32_bf16(W3f[kb], B3, a3, 0, 0, 0);
            }
            // mask + accumulate into bounce [ch][64 px]
            const float svv = sv[sub];
#pragma unroll
            for (int r4 = 0; r4 < 4; ++r4)
                bounce[(q * 4 + r4) * 64 + sub * 16 + ln] = a3[r4] * svv;
        }
        // ---- stores: per channel, 64 lanes x 4B = full aligned 256 B line ----
        {
            float* orow = out + (((size_t)(bb * 16)) << 16) + (size_t)r * 256
                        + (wv & 3) * 64 + lane;
#pragma unroll
            for (int ch = 0; ch < 16; ++ch)
                orow[(size_t)ch << 16] = bounce[ch * 64 + lane];
        }
    }
}

extern "C" void kernel_launch(void* const* d_in, const int* in_sizes, int n_in,
                              void* d_out, int out_size, void* d_ws, size_t ws_size,
                              hipStream_t stream) {
    (void)in_sizes; (void)n_in; (void)out_size; (void)ws_size;
    const float* x  = (const float*)d_in[0];
    const float* fm = (const float*)d_in[1];
    const float* w1 = (const float*)d_in[2];
    const float* b1 = (const float*)d_in[3];
    const float* w2 = (const float*)d_in[4];
    const float* b2 = (const float*)d_in[5];
    const float* w3 = (const float*)d_in[6];
    const float* b3 = (const float*)d_in[7];
    float* o = (float*)d_out;
    unsigned short* ws = (unsigned short*)d_ws;

    prep_weights<<<dim3(13), dim3(256), 0, stream>>>(w1, b1, w2, w3, ws);

    hipFuncSetAttribute((const void*)fused_kernel,
                        hipFuncAttributeMaxDynamicSharedMemorySize, SM_TOTAL);
    fused_kernel<<<dim3(512), dim3(512), SM_TOTAL, stream>>>(x, fm, ws, b2, b3, o);
}